// Round 1
// 1128.900 us; speedup vs baseline: 1.0221x; 1.0221x over previous
//
#include <hip/hip_runtime.h>
#include <stdint.h>
#include <float.h>

// PillarFeatureNet on MI355X — round 9: compact shrunk to 4B/channel via
// gamma-sign preselection (sign(scale)=sign(gamma) since rsqrt>0), merged
// pillar descriptor (one uint4 broadcast load), float4-vectorized canvas
// stores in k_expand.
// B=2, T=5, GX=GY=512, C=64, N=600000. Output (B,C,T,GY,GX) f32 = 671 MB.
//
// Algebra: xc = pbase(point) - md(pillar,ch), where
//   pbase = x(w0+w4+w7) + y(w1+w5+w8) + z(w2+w6) + it*w3 - (ctr0*w7+ctr1*w8)
//   md    = m0*w4 + m1*w5 + m2*w6           (m = pillar xyz mean)
// max_p xc = max_p pbase - md (exact); BN stats via
//   Sum xc   = Sum pb  - cnt*md
//   Sum xc^2 = Sum pb^2 - 2 md Sum pb + cnt md^2
// scale = gamma*rsqrt(var+eps): rsqrt>0, so the post-BN argmax over a
// pillar is max(pb) if gamma>=0 else min(pb) — selectable BEFORE stats.
// Voxelization numerics: (x+51.2f)*5.0f IEEE-pinned f32 — membership-
// critical, matches the oracle's multiply-by-reciprocal. DO NOT TOUCH.

#define GXc 512
#define GYc 512
#define Bc  2
#define Tc  5
#define Cc  64
#define NSEG (Bc * Tc * GYc * GXc)   // 2,621,440
#define SBc 2048                     // stat partial rows (= k_pillar grid)

__device__ __forceinline__ bool point_prep(const float* __restrict__ p,
    float& x, float& y, float& z, float& inten,
    int& bid, int& tid, int& cx, int& cy, int& seg)
{
    float b0 = p[0];
    x = p[1]; y = p[2]; z = p[3]; inten = p[4];
    float tf = p[5];
    float cf0 = __fmul_rn(__fadd_rn(x, 51.2f), 5.0f);
    float cf1 = __fmul_rn(__fadd_rn(y, 51.2f), 5.0f);
    bool valid = (cf0 >= 0.0f) && (cf0 < 512.0f) && (cf1 >= 0.0f) && (cf1 < 512.0f);
    int icx = (int)cf0; icx = icx < 0 ? 0 : (icx > GXc - 1 ? GXc - 1 : icx);
    int icy = (int)cf1; icy = icy < 0 ? 0 : (icy > GYc - 1 ? GYc - 1 : icy);
    cx = icx; cy = icy;
    bid = (int)b0;
    tid = (int)tf;
    seg = ((bid * Tc + tid) * GYc + cy) * GXc + cx;
    return valid;
}

// srArr[i] = {seg, rank} ({0xFFFFFFFF,0} if invalid)
extern "C" __global__ __launch_bounds__(256)
void k_count(const float* __restrict__ pts, uint32_t* __restrict__ counts,
             uint2* __restrict__ srArr, int n)
{
    int i = blockIdx.x * 256 + threadIdx.x;
    if (i >= n) return;
    float x, y, z, it; int bid, tid, cx, cy, seg;
    bool v = point_prep(pts + (size_t)i * 6, x, y, z, it, bid, tid, cx, cy, seg);
    if (!v) { srArr[i] = make_uint2(0xFFFFFFFFu, 0u); return; }
    uint32_t r = atomicAdd(&counts[seg], 1u);
    srArr[i] = make_uint2((uint32_t)seg, r);
}

// Dense-id + offset assignment via block scan; ONE u64 atomic per block.
// ctr[2..3] = packed u64 (low32 = total valid points, high32 = nPillars).
// Emits per-dense qdesc = {off, cnt, seg, 0} for k_pillar (single load).
extern "C" __global__ __launch_bounds__(1024)
void k_offsets(const uint32_t* __restrict__ counts, uint32_t* __restrict__ ctr,
               int* __restrict__ denseOf, uint32_t* __restrict__ offOf,
               uint4* __restrict__ qdesc)
{
    int tid = threadIdx.x;
    int i = blockIdx.x * 1024 + tid;
    uint32_t cnt = (i < NSEG) ? counts[i] : 0u;
    uint32_t occ = (cnt > 0u) ? 1u : 0u;
    unsigned long long v = ((unsigned long long)occ << 32) | (unsigned long long)cnt;
    unsigned long long inc = v;
    int lane = tid & 63, wid = tid >> 6;
    #pragma unroll
    for (int d = 1; d < 64; d <<= 1) {
        unsigned long long t = __shfl_up(inc, d, 64);
        if (lane >= d) inc += t;
    }
    __shared__ unsigned long long wtot[16];
    __shared__ unsigned long long wbase[16];
    __shared__ unsigned long long gbase;
    if (lane == 63) wtot[wid] = inc;
    __syncthreads();
    if (wid == 0) {
        unsigned long long w = (lane < 16) ? wtot[lane] : 0ull;
        unsigned long long s = w;
        #pragma unroll
        for (int d = 1; d < 16; d <<= 1) {
            unsigned long long t = __shfl_up(s, d, 64);
            if (lane >= d) s += t;
        }
        if (lane < 16) wbase[lane] = s - w;
        if (lane == 15)
            gbase = atomicAdd((unsigned long long*)(ctr + 2), s);
    }
    __syncthreads();
    if (i >= NSEG) return;
    unsigned long long ex = gbase + wbase[wid] + (inc - v);
    if (occ) {
        uint32_t d = (uint32_t)(ex >> 32);
        uint32_t o = (uint32_t)ex;
        denseOf[i] = (int)d;
        offOf[i] = o;
        qdesc[d] = make_uint4(o, cnt, (uint32_t)i, 0u);
    } else {
        denseOf[i] = -1;
    }
}

// Deposit point payload (x,y,z,inten) into its pillar's list slot.
extern "C" __global__ __launch_bounds__(256)
void k_fill(const float* __restrict__ pts, const uint2* __restrict__ srArr,
            const uint32_t* __restrict__ offOf, float4* __restrict__ list4, int n)
{
    int i = blockIdx.x * 256 + threadIdx.x;
    if (i >= n) return;
    uint2 sr = srArr[i];
    if (sr.x == 0xFFFFFFFFu) return;
    const float* P = pts + (size_t)i * 6;
    list4[offOf[sr.x] + sr.y] = make_float4(P[1], P[2], P[3], P[4]);
}

// Grid-stride over occupied pillars; one wave per pillar, lane = channel.
// SINGLE pass per pillar: one float4 load per point; pbase reduction;
// gamma-sign preselected extremum stored (4B/channel); f64 BN-stat
// partials per block.
extern "C" __global__ __launch_bounds__(256)
void k_pillar(const float4* __restrict__ list4, const uint4* __restrict__ qdesc,
              const float* __restrict__ W, const float* __restrict__ gamma,
              const uint32_t* __restrict__ ctr, float* __restrict__ compact,
              double* __restrict__ px, double* __restrict__ px2)
{
    int lane = threadIdx.x & 63;
    int sub  = threadIdx.x >> 6;
    uint32_t nP = ctr[3];                       // high32 of packed counter
    float w0 = W[0 * Cc + lane], w1 = W[1 * Cc + lane], w2 = W[2 * Cc + lane];
    float w3 = W[3 * Cc + lane], w4 = W[4 * Cc + lane], w5 = W[5 * Cc + lane];
    float w6 = W[6 * Cc + lane], w7 = W[7 * Cc + lane], w8 = W[8 * Cc + lane];
    float wx = w0 + w4 + w7, wy = w1 + w5 + w8, wz = w2 + w6;
    // sign(scale) = sign(gamma) since rsqrt(var+eps) > 0: pick extremum now.
    float sgn = (gamma[lane] >= 0.0f) ? 1.0f : -1.0f;
    double ax = 0.0, ax2 = 0.0;
    for (uint32_t d = blockIdx.x * 4 + sub; d < nP; d += (uint32_t)gridDim.x * 4) {
        uint4 q = qdesc[d];
        uint32_t off = q.x, cnt = q.y;
        int seg = (int)q.z;
        int cx = seg & (GXc - 1);
        int cy = (seg >> 9) & (GYc - 1);
        float ctr0 = __fadd_rn(__fadd_rn(__fmul_rn((float)cx, 0.2f), 0.1f), -51.2f);
        float ctr1 = __fadd_rn(__fadd_rn(__fmul_rn((float)cy, 0.2f), 0.1f), -51.2f);
        float cconst = -(ctr0 * w7 + ctr1 * w8);
        float sx = 0.f, sy = 0.f, sz = 0.f;
        float m = -FLT_MAX;                      // running max of sgn*pb
        double spb = 0.0, spb2 = 0.0;
        for (uint32_t p = 0; p < cnt; p++) {
            float4 P = list4[off + p];
            sx += P.x; sy += P.y; sz += P.z;
            float pb = fmaf(P.x, wx,
                       fmaf(P.y, wy,
                       fmaf(P.z, wz,
                       fmaf(P.w, w3, cconst))));
            m = fmaxf(m, sgn * pb);              // sign flip is exact
            spb += (double)pb;
            spb2 = fma((double)pb, (double)pb, spb2);
        }
        float fc = (float)cnt;
        float m0 = sx / fc, m1 = sy / fc, m2 = sz / fc;
        float md = fmaf(m0, w4, fmaf(m1, w5, m2 * w6));
        compact[(size_t)d * 64 + lane] = sgn * m - md;   // sgn*m == max or min of pb
        double mdd = (double)md, cd = (double)cnt;
        ax  += spb - cd * mdd;
        ax2 += spb2 - 2.0 * mdd * spb + cd * mdd * mdd;
    }
    __shared__ double sred[256];
    sred[threadIdx.x] = ax;
    __syncthreads();
    if (sub == 0)
        px[(size_t)blockIdx.x * 64 + lane] =
            sred[lane] + sred[lane + 64] + sred[lane + 128] + sred[lane + 192];
    __syncthreads();
    sred[threadIdx.x] = ax2;
    __syncthreads();
    if (sub == 0)
        px2[(size_t)blockIdx.x * 64 + lane] =
            sred[lane] + sred[lane + 64] + sred[lane + 128] + sred[lane + 192];
}

extern "C" __global__ __launch_bounds__(256)
void k_finalize(const double* __restrict__ px, const double* __restrict__ px2,
                const uint32_t* __restrict__ ctr,
                const float* __restrict__ gamma, const float* __restrict__ beta,
                float* __restrict__ scale, float* __restrict__ shift)
{
    int c = threadIdx.x & 63;
    int g = threadIdx.x >> 6;
    double sx = 0.0, sx2 = 0.0;
    for (int b = g; b < SBc; b += 4) {
        sx  += px[(size_t)b * 64 + c];
        sx2 += px2[(size_t)b * 64 + c];
    }
    __shared__ double sr[256];
    sr[threadIdx.x] = sx;
    __syncthreads();
    double tsx = 0.0;
    if (g == 0) tsx = sr[c] + sr[c + 64] + sr[c + 128] + sr[c + 192];
    __syncthreads();
    sr[threadIdx.x] = sx2;
    __syncthreads();
    if (g == 0) {
        double tsx2 = sr[c] + sr[c + 64] + sr[c + 128] + sr[c + 192];
        uint32_t nvu = ctr[2];                 // low32 of packed = nvalid
        if (nvu < 1u) nvu = 1u;
        double nv = (double)nvu;
        double mu = tsx / nv;
        double var = tsx2 / nv - mu * mu;
        float r = (float)(1.0 / sqrt(var + 0.001));
        float sc = gamma[c] * r;
        scale[c] = sc;
        shift[c] = fmaf(-(float)mu, sc, beta[c]);
    }
}

// Expand compact -> full canvas: v = relu(val*scale + shift); empty -> 0.
// Gather phase: wave reads 256B contiguous compact rows (dense ids are
// consecutive in seg order). Write phase: float4 stores, 1KB per wave-op.
extern "C" __global__ __launch_bounds__(256)
void k_expand(const float* __restrict__ compact, const int* __restrict__ denseOf,
              const float* __restrict__ scale, const float* __restrict__ shift,
              float* __restrict__ out)
{
    __shared__ int sdense[128];
    __shared__ float tile[128 * 65];
    int tid = threadIdx.x;
    int s0 = blockIdx.x * 128;
    if (tid < 128) sdense[tid] = denseOf[s0 + tid];
    __syncthreads();
    int w = tid >> 6, lane = tid & 63;
    float sc = scale[lane], sh = shift[lane];
    for (int k = 0; k < 32; k++) {
        int p = w * 32 + k;
        int d = sdense[p];
        float v = 0.0f;
        if (d >= 0) {
            float val = compact[(size_t)d * 64 + lane];
            v = fmaxf(fmaf(val, sc, sh), 0.0f);
        }
        tile[p * 65 + lane] = v;
    }
    __syncthreads();
    int gx0 = s0 & (GXc - 1);
    int gy  = (s0 >> 9) & (GYc - 1);
    int bt  = s0 >> 18;            // b*T + t
    int t   = bt % Tc;
    int b   = bt / Tc;
    int q   = tid & 31;            // gx quad index
    int cq  = tid >> 5;            // 0..7: channel sub-index
    size_t rowbase = ((size_t)gy << 9) + gx0 + q * 4;
    #pragma unroll
    for (int cc = 0; cc < 64; cc += 8) {
        int c = cc + cq;
        float4 vv;
        vv.x = tile[(q * 4 + 0) * 65 + c];
        vv.y = tile[(q * 4 + 1) * 65 + c];
        vv.z = tile[(q * 4 + 2) * 65 + c];
        vv.w = tile[(q * 4 + 3) * 65 + c];
        size_t o = ((((size_t)b * Cc + c) * Tc + t) << 18) + rowbase;
        *reinterpret_cast<float4*>(out + o) = vv;
    }
}

extern "C" void kernel_launch(void* const* d_in, const int* in_sizes, int n_in,
                              void* d_out, int out_size, void* d_ws, size_t ws_size,
                              hipStream_t stream)
{
    const float* pts   = (const float*)d_in[0];
    const float* W     = (const float*)d_in[1];
    const float* gamma = (const float*)d_in[2];
    const float* beta  = (const float*)d_in[3];
    int n = in_sizes[0] / 6;

    uint8_t* ws = (uint8_t*)d_ws;
    size_t npad = ((size_t)n * 4 + 255) & ~(size_t)255;
    const size_t OFF_CTR    = 0;                                   // 256 B
    const size_t OFF_COUNTS = 256;
    const size_t ZERO_END   = OFF_COUNTS + (size_t)NSEG * 4;       // 10.5 MB
    const size_t OFF_PX     = ZERO_END;
    const size_t OFF_PX2    = OFF_PX  + (size_t)SBc * 64 * 8;
    const size_t OFF_SCALE  = OFF_PX2 + (size_t)SBc * 64 * 8;
    const size_t OFF_SHIFT  = OFF_SCALE + 256;
    const size_t OFF_DENSE  = OFF_SHIFT + 256;
    const size_t OFF_OFFOF  = OFF_DENSE + (size_t)NSEG * 4;
    const size_t OFF_QDESC  = OFF_OFFOF + (size_t)NSEG * 4;        // uint4[NSEG]
    const size_t OFF_SR     = OFF_QDESC + (size_t)NSEG * 16;       // uint2[n]
    const size_t OFF_LIST   = OFF_SR + npad * 2;                   // float4[n]
    const size_t OFF_COMP   = OFF_LIST + npad * 4;                 // float[nP][64]

    uint32_t* ctr     = (uint32_t*)(ws + OFF_CTR);
    uint32_t* counts  = (uint32_t*)(ws + OFF_COUNTS);
    double*   px      = (double*)(ws + OFF_PX);
    double*   px2     = (double*)(ws + OFF_PX2);
    float*    scale   = (float*)(ws + OFF_SCALE);
    float*    shift   = (float*)(ws + OFF_SHIFT);
    int*      denseOf = (int*)(ws + OFF_DENSE);
    uint32_t* offOf   = (uint32_t*)(ws + OFF_OFFOF);
    uint4*    qdesc   = (uint4*)(ws + OFF_QDESC);
    uint2*    srArr   = (uint2*)(ws + OFF_SR);
    float4*   list4   = (float4*)(ws + OFF_LIST);
    float*    compact = (float*)(ws + OFF_COMP);

    hipMemsetAsync(ws, 0, ZERO_END, stream);   // ctr + counts only (10.5 MB)

    k_count   <<<(n + 255) / 256, 256, 0, stream>>>(pts, counts, srArr, n);
    k_offsets <<<(NSEG + 1023) / 1024, 1024, 0, stream>>>(counts, ctr, denseOf,
                                                          offOf, qdesc);
    k_fill    <<<(n + 255) / 256, 256, 0, stream>>>(pts, srArr, offOf, list4, n);
    k_pillar  <<<SBc, 256, 0, stream>>>(list4, qdesc, W, gamma, ctr,
                                        compact, px, px2);
    k_finalize<<<1, 256, 0, stream>>>(px, px2, ctr, gamma, beta, scale, shift);
    k_expand  <<<NSEG / 128, 256, 0, stream>>>(compact, denseOf, scale, shift,
                                               (float*)d_out);
}

// Round 3
// 983.467 us; speedup vs baseline: 1.1732x; 1.1479x over previous
//
#include <hip/hip_runtime.h>
#include <stdint.h>
#include <float.h>

// PillarFeatureNet on MI355X — round 10b: non-temporal canvas stores (keep
// compact LLC-resident for its re-read), float2-vectorized point loads,
// rank-only side array (seg recomputed in k_fill from the pts re-read).
// Fix vs r10: __builtin_nontemporal_store needs a clang ext-vector type,
// not HIP's float4 class.
// B=2, T=5, GX=GY=512, C=64, N=600000. Output (B,C,T,GY,GX) f32 = 671 MB.
//
// Timing model (r10): dur_us includes two ~2.5GiB harness poison fills
// (~850 us fixed). Controllable slice ~280 us vs ~170 us traffic floor.
//
// Algebra: xc = pbase(point) - md(pillar,ch), where
//   pbase = x(w0+w4+w7) + y(w1+w5+w8) + z(w2+w6) + it*w3 - (ctr0*w7+ctr1*w8)
//   md    = m0*w4 + m1*w5 + m2*w6           (m = pillar xyz mean)
// max_p xc = max_p pbase - md (exact); BN stats via
//   Sum xc   = Sum pb  - cnt*md
//   Sum xc^2 = Sum pb^2 - 2 md Sum pb + cnt md^2
// scale = gamma*rsqrt(var+eps): rsqrt>0, so the post-BN argmax over a
// pillar is max(pb) if gamma>=0 else min(pb) — selectable BEFORE stats.
// Voxelization numerics: (x+51.2f)*5.0f IEEE-pinned f32 — membership-
// critical, matches the oracle's multiply-by-reciprocal. DO NOT TOUCH.

#define GXc 512
#define GYc 512
#define Bc  2
#define Tc  5
#define Cc  64
#define NSEG (Bc * Tc * GYc * GXc)   // 2,621,440
#define SBc 2048                     // stat partial rows (= k_pillar grid)

typedef float nfloat4 __attribute__((ext_vector_type(4)));

// Vectorized 6-float point load: three aligned float2s (24B stride -> 8B ok).
__device__ __forceinline__ void load_pt(const float* __restrict__ p,
    float& b0, float& x, float& y, float& z, float& inten, float& tf)
{
    const float2* p2 = reinterpret_cast<const float2*>(p);
    float2 a = p2[0], b = p2[1], c = p2[2];
    b0 = a.x; x = a.y; y = b.x; z = b.y; inten = c.x; tf = c.y;
}

__device__ __forceinline__ bool voxelize(float b0, float x, float y, float tf,
                                         int& seg)
{
    float cf0 = __fmul_rn(__fadd_rn(x, 51.2f), 5.0f);
    float cf1 = __fmul_rn(__fadd_rn(y, 51.2f), 5.0f);
    bool valid = (cf0 >= 0.0f) && (cf0 < 512.0f) && (cf1 >= 0.0f) && (cf1 < 512.0f);
    int icx = (int)cf0; icx = icx < 0 ? 0 : (icx > GXc - 1 ? GXc - 1 : icx);
    int icy = (int)cf1; icy = icy < 0 ? 0 : (icy > GYc - 1 ? GYc - 1 : icy);
    int bid = (int)b0;
    int tid = (int)tf;
    seg = ((bid * Tc + tid) * GYc + icy) * GXc + icx;
    return valid;
}

// rank[i] = atomic rank within pillar (untouched for invalid points).
extern "C" __global__ __launch_bounds__(256)
void k_count(const float* __restrict__ pts, uint32_t* __restrict__ counts,
             uint32_t* __restrict__ rank, int n)
{
    int i = blockIdx.x * 256 + threadIdx.x;
    if (i >= n) return;
    float b0, x, y, z, it, tf; int seg;
    load_pt(pts + (size_t)i * 6, b0, x, y, z, it, tf);
    if (!voxelize(b0, x, y, tf, seg)) return;
    rank[i] = atomicAdd(&counts[seg], 1u);
}

// Dense-id + offset assignment via block scan; ONE u64 atomic per block.
// ctr[2..3] = packed u64 (low32 = total valid points, high32 = nPillars).
// Emits per-dense qdesc = {off, cnt, seg, 0} for k_pillar (single load).
extern "C" __global__ __launch_bounds__(1024)
void k_offsets(const uint32_t* __restrict__ counts, uint32_t* __restrict__ ctr,
               int* __restrict__ denseOf, uint32_t* __restrict__ offOf,
               uint4* __restrict__ qdesc)
{
    int tid = threadIdx.x;
    int i = blockIdx.x * 1024 + tid;
    uint32_t cnt = (i < NSEG) ? counts[i] : 0u;
    uint32_t occ = (cnt > 0u) ? 1u : 0u;
    unsigned long long v = ((unsigned long long)occ << 32) | (unsigned long long)cnt;
    unsigned long long inc = v;
    int lane = tid & 63, wid = tid >> 6;
    #pragma unroll
    for (int d = 1; d < 64; d <<= 1) {
        unsigned long long t = __shfl_up(inc, d, 64);
        if (lane >= d) inc += t;
    }
    __shared__ unsigned long long wtot[16];
    __shared__ unsigned long long wbase[16];
    __shared__ unsigned long long gbase;
    if (lane == 63) wtot[wid] = inc;
    __syncthreads();
    if (wid == 0) {
        unsigned long long w = (lane < 16) ? wtot[lane] : 0ull;
        unsigned long long s = w;
        #pragma unroll
        for (int d = 1; d < 16; d <<= 1) {
            unsigned long long t = __shfl_up(s, d, 64);
            if (lane >= d) s += t;
        }
        if (lane < 16) wbase[lane] = s - w;
        if (lane == 15)
            gbase = atomicAdd((unsigned long long*)(ctr + 2), s);
    }
    __syncthreads();
    if (i >= NSEG) return;
    unsigned long long ex = gbase + wbase[wid] + (inc - v);
    if (occ) {
        uint32_t d = (uint32_t)(ex >> 32);
        uint32_t o = (uint32_t)ex;
        denseOf[i] = (int)d;
        offOf[i] = o;
        qdesc[d] = make_uint4(o, cnt, (uint32_t)i, 0u);
    } else {
        denseOf[i] = -1;
    }
}

// Deposit point payload (x,y,z,inten) into its pillar's list slot.
// seg/validity recomputed from the (anyway-needed) pts read.
extern "C" __global__ __launch_bounds__(256)
void k_fill(const float* __restrict__ pts, const uint32_t* __restrict__ rank,
            const uint32_t* __restrict__ offOf, float4* __restrict__ list4, int n)
{
    int i = blockIdx.x * 256 + threadIdx.x;
    if (i >= n) return;
    float b0, x, y, z, it, tf; int seg;
    load_pt(pts + (size_t)i * 6, b0, x, y, z, it, tf);
    if (!voxelize(b0, x, y, tf, seg)) return;
    uint32_t r = rank[i];
    list4[offOf[seg] + r] = make_float4(x, y, z, it);
}

// Grid-stride over occupied pillars; one wave per pillar, lane = channel.
// SINGLE pass per pillar: one float4 load per point; pbase reduction;
// gamma-sign preselected extremum stored (4B/channel); f64 BN-stat
// partials per block.
extern "C" __global__ __launch_bounds__(256)
void k_pillar(const float4* __restrict__ list4, const uint4* __restrict__ qdesc,
              const float* __restrict__ W, const float* __restrict__ gamma,
              const uint32_t* __restrict__ ctr, float* __restrict__ compact,
              double* __restrict__ px, double* __restrict__ px2)
{
    int lane = threadIdx.x & 63;
    int sub  = threadIdx.x >> 6;
    uint32_t nP = ctr[3];                       // high32 of packed counter
    float w0 = W[0 * Cc + lane], w1 = W[1 * Cc + lane], w2 = W[2 * Cc + lane];
    float w3 = W[3 * Cc + lane], w4 = W[4 * Cc + lane], w5 = W[5 * Cc + lane];
    float w6 = W[6 * Cc + lane], w7 = W[7 * Cc + lane], w8 = W[8 * Cc + lane];
    float wx = w0 + w4 + w7, wy = w1 + w5 + w8, wz = w2 + w6;
    // sign(scale) = sign(gamma) since rsqrt(var+eps) > 0: pick extremum now.
    float sgn = (gamma[lane] >= 0.0f) ? 1.0f : -1.0f;
    double ax = 0.0, ax2 = 0.0;
    for (uint32_t d = blockIdx.x * 4 + sub; d < nP; d += (uint32_t)gridDim.x * 4) {
        uint4 q = qdesc[d];
        uint32_t off = q.x, cnt = q.y;
        int seg = (int)q.z;
        int cx = seg & (GXc - 1);
        int cy = (seg >> 9) & (GYc - 1);
        float ctr0 = __fadd_rn(__fadd_rn(__fmul_rn((float)cx, 0.2f), 0.1f), -51.2f);
        float ctr1 = __fadd_rn(__fadd_rn(__fmul_rn((float)cy, 0.2f), 0.1f), -51.2f);
        float cconst = -(ctr0 * w7 + ctr1 * w8);
        float sx = 0.f, sy = 0.f, sz = 0.f;
        float m = -FLT_MAX;                      // running max of sgn*pb
        double spb = 0.0, spb2 = 0.0;
        for (uint32_t p = 0; p < cnt; p++) {
            float4 P = list4[off + p];
            sx += P.x; sy += P.y; sz += P.z;
            float pb = fmaf(P.x, wx,
                       fmaf(P.y, wy,
                       fmaf(P.z, wz,
                       fmaf(P.w, w3, cconst))));
            m = fmaxf(m, sgn * pb);              // sign flip is exact
            spb += (double)pb;
            spb2 = fma((double)pb, (double)pb, spb2);
        }
        float fc = (float)cnt;
        float m0 = sx / fc, m1 = sy / fc, m2 = sz / fc;
        float md = fmaf(m0, w4, fmaf(m1, w5, m2 * w6));
        compact[(size_t)d * 64 + lane] = sgn * m - md;   // sgn*m == max or min of pb
        double mdd = (double)md, cd = (double)cnt;
        ax  += spb - cd * mdd;
        ax2 += spb2 - 2.0 * mdd * spb + cd * mdd * mdd;
    }
    __shared__ double sred[256];
    sred[threadIdx.x] = ax;
    __syncthreads();
    if (sub == 0)
        px[(size_t)blockIdx.x * 64 + lane] =
            sred[lane] + sred[lane + 64] + sred[lane + 128] + sred[lane + 192];
    __syncthreads();
    sred[threadIdx.x] = ax2;
    __syncthreads();
    if (sub == 0)
        px2[(size_t)blockIdx.x * 64 + lane] =
            sred[lane] + sred[lane + 64] + sred[lane + 128] + sred[lane + 192];
}

extern "C" __global__ __launch_bounds__(256)
void k_finalize(const double* __restrict__ px, const double* __restrict__ px2,
                const uint32_t* __restrict__ ctr,
                const float* __restrict__ gamma, const float* __restrict__ beta,
                float* __restrict__ scale, float* __restrict__ shift)
{
    int c = threadIdx.x & 63;
    int g = threadIdx.x >> 6;
    double sx = 0.0, sx2 = 0.0;
    for (int b = g; b < SBc; b += 4) {
        sx  += px[(size_t)b * 64 + c];
        sx2 += px2[(size_t)b * 64 + c];
    }
    __shared__ double sr[256];
    sr[threadIdx.x] = sx;
    __syncthreads();
    double tsx = 0.0;
    if (g == 0) tsx = sr[c] + sr[c + 64] + sr[c + 128] + sr[c + 192];
    __syncthreads();
    sr[threadIdx.x] = sx2;
    __syncthreads();
    if (g == 0) {
        double tsx2 = sr[c] + sr[c + 64] + sr[c + 128] + sr[c + 192];
        uint32_t nvu = ctr[2];                 // low32 of packed = nvalid
        if (nvu < 1u) nvu = 1u;
        double nv = (double)nvu;
        double mu = tsx / nv;
        double var = tsx2 / nv - mu * mu;
        float r = (float)(1.0 / sqrt(var + 0.001));
        float sc = gamma[c] * r;
        scale[c] = sc;
        shift[c] = fmaf(-(float)mu, sc, beta[c]);
    }
}

// Expand compact -> full canvas: v = relu(val*scale + shift); empty -> 0.
// Gather phase: wave reads 256B contiguous compact rows. Write phase:
// NON-TEMPORAL float4 stores (canvas is write-once, never re-read by us;
// keeping it out of LLC preserves compact residency for the gather).
extern "C" __global__ __launch_bounds__(256)
void k_expand(const float* __restrict__ compact, const int* __restrict__ denseOf,
              const float* __restrict__ scale, const float* __restrict__ shift,
              float* __restrict__ out)
{
    __shared__ int sdense[128];
    __shared__ float tile[128 * 65];
    int tid = threadIdx.x;
    int s0 = blockIdx.x * 128;
    if (tid < 128) sdense[tid] = denseOf[s0 + tid];
    __syncthreads();
    int w = tid >> 6, lane = tid & 63;
    float sc = scale[lane], sh = shift[lane];
    for (int k = 0; k < 32; k++) {
        int p = w * 32 + k;
        int d = sdense[p];
        float v = 0.0f;
        if (d >= 0) {
            float val = compact[(size_t)d * 64 + lane];
            v = fmaxf(fmaf(val, sc, sh), 0.0f);
        }
        tile[p * 65 + lane] = v;
    }
    __syncthreads();
    int gx0 = s0 & (GXc - 1);
    int gy  = (s0 >> 9) & (GYc - 1);
    int bt  = s0 >> 18;            // b*T + t
    int t   = bt % Tc;
    int b   = bt / Tc;
    int q   = tid & 31;            // gx quad index
    int cq  = tid >> 5;            // 0..7: channel sub-index
    size_t rowbase = ((size_t)gy << 9) + gx0 + q * 4;
    #pragma unroll
    for (int cc = 0; cc < 64; cc += 8) {
        int c = cc + cq;
        nfloat4 vv;
        vv.x = tile[(q * 4 + 0) * 65 + c];
        vv.y = tile[(q * 4 + 1) * 65 + c];
        vv.z = tile[(q * 4 + 2) * 65 + c];
        vv.w = tile[(q * 4 + 3) * 65 + c];
        size_t o = ((((size_t)b * Cc + c) * Tc + t) << 18) + rowbase;
        __builtin_nontemporal_store(vv, reinterpret_cast<nfloat4*>(out + o));
    }
}

extern "C" void kernel_launch(void* const* d_in, const int* in_sizes, int n_in,
                              void* d_out, int out_size, void* d_ws, size_t ws_size,
                              hipStream_t stream)
{
    const float* pts   = (const float*)d_in[0];
    const float* W     = (const float*)d_in[1];
    const float* gamma = (const float*)d_in[2];
    const float* beta  = (const float*)d_in[3];
    int n = in_sizes[0] / 6;

    uint8_t* ws = (uint8_t*)d_ws;
    size_t npad = ((size_t)n * 4 + 255) & ~(size_t)255;
    const size_t OFF_CTR    = 0;                                   // 256 B
    const size_t OFF_COUNTS = 256;
    const size_t ZERO_END   = OFF_COUNTS + (size_t)NSEG * 4;       // 10.5 MB
    const size_t OFF_PX     = ZERO_END;
    const size_t OFF_PX2    = OFF_PX  + (size_t)SBc * 64 * 8;
    const size_t OFF_SCALE  = OFF_PX2 + (size_t)SBc * 64 * 8;
    const size_t OFF_SHIFT  = OFF_SCALE + 256;
    const size_t OFF_DENSE  = OFF_SHIFT + 256;
    const size_t OFF_OFFOF  = OFF_DENSE + (size_t)NSEG * 4;
    const size_t OFF_QDESC  = OFF_OFFOF + (size_t)NSEG * 4;        // uint4[NSEG]
    const size_t OFF_RANK   = OFF_QDESC + (size_t)NSEG * 16;       // u32[n]
    const size_t OFF_LIST   = OFF_RANK + npad;                     // float4[n]
    const size_t OFF_COMP   = OFF_LIST + npad * 4;                 // float[nP][64]

    uint32_t* ctr     = (uint32_t*)(ws + OFF_CTR);
    uint32_t* counts  = (uint32_t*)(ws + OFF_COUNTS);
    double*   px      = (double*)(ws + OFF_PX);
    double*   px2     = (double*)(ws + OFF_PX2);
    float*    scale   = (float*)(ws + OFF_SCALE);
    float*    shift   = (float*)(ws + OFF_SHIFT);
    int*      denseOf = (int*)(ws + OFF_DENSE);
    uint32_t* offOf   = (uint32_t*)(ws + OFF_OFFOF);
    uint4*    qdesc   = (uint4*)(ws + OFF_QDESC);
    uint32_t* rank    = (uint32_t*)(ws + OFF_RANK);
    float4*   list4   = (float4*)(ws + OFF_LIST);
    float*    compact = (float*)(ws + OFF_COMP);

    hipMemsetAsync(ws, 0, ZERO_END, stream);   // ctr + counts only (10.5 MB)

    k_count   <<<(n + 255) / 256, 256, 0, stream>>>(pts, counts, rank, n);
    k_offsets <<<(NSEG + 1023) / 1024, 1024, 0, stream>>>(counts, ctr, denseOf,
                                                          offOf, qdesc);
    k_fill    <<<(n + 255) / 256, 256, 0, stream>>>(pts, rank, offOf, list4, n);
    k_pillar  <<<SBc, 256, 0, stream>>>(list4, qdesc, W, gamma, ctr,
                                        compact, px, px2);
    k_finalize<<<1, 256, 0, stream>>>(px, px2, ctr, gamma, beta, scale, shift);
    k_expand  <<<NSEG / 128, 256, 0, stream>>>(compact, denseOf, scale, shift,
                                               (float*)d_out);
}